// Round 1
// baseline (2682.306 us; speedup 1.0000x reference)
//
#include <hip/hip_runtime.h>
#include <math.h>

#define DM   272
#define DS   32
#define DI   544
#define DTR  17
#define SEQL 512
#define NB   2
#define ROWS 1024
#define DXZ  1088
#define NL   12

// workspace offsets (in floats)
#define OFF_X     0          // 1024*272
#define OFF_INVR  278528     // 1024
#define OFF_XZ    279552     // 2*2*512*1088
#define OFF_XC    2507776    // 2*2*512*544
#define OFF_DT    3621888    // 2*2*512*544
#define OFF_BM    4736000    // 2*2*512*32
#define OFF_CM    4801536    // 2*2*512*32
#define OFF_YO    4867072    // 2*2*512*544
#define OFF_Y12   5981184    // 2*1024*272
#define OFF_XMP   6538240    // 16*272
// end: 6542592 floats = 26.2 MB

__device__ __forceinline__ float sigmoid_fast(float x){ return 1.f/(1.f+__expf(-x)); }

__device__ __forceinline__ float block_reduce_256(float v, volatile float* sred, int tid){
#pragma unroll
  for (int m=32; m>=1; m>>=1) v += __shfl_xor(v, m);
  __syncthreads();
  if ((tid & 63) == 0) sred[tid>>6] = v;
  __syncthreads();
  return sred[0]+sred[1]+sred[2]+sred[3];
}

// ---------------------------------------------------------------- init: copy x, per-row invrms
__global__ __launch_bounds__(64) void k_init(const float* __restrict__ x0,
                                             float* __restrict__ xb, float* __restrict__ invr){
  int r = blockIdx.x, tid = threadIdx.x;
  float ss = 0.f;
  for (int c=tid; c<DM; c+=64){ float v = x0[(size_t)r*DM+c]; xb[(size_t)r*DM+c]=v; ss += v*v; }
#pragma unroll
  for (int m=32;m>=1;m>>=1) ss += __shfl_xor(ss,m);
  if (tid==0) invr[r] = rsqrtf(ss*(1.f/DM)+1e-5f);
}

// ---------------------------------------------------------------- in_proj GEMM (rmsnorm fused)
// C[1024 x 2176] = xn[1024 x 272] @ W^T ; dir1 rows stored time-flipped
__global__ __launch_bounds__(256) void k_inproj(
    const float* __restrict__ xb, const float* __restrict__ invr,
    const float* __restrict__ n1w, const float* __restrict__ inw,
    float* __restrict__ xz)
{
  __shared__ float As[16][76];
  __shared__ float Bs[16][76];
  const int tid = threadIdx.x;
  const int m0 = blockIdx.x << 6;
  const int nt = blockIdx.y;                    // 0..33
  const int dir = (nt >= 17) ? 1 : 0;
  const int n0l = (nt - dir*17) << 6;           // local col within dir
  const float* wb = inw + (size_t)(dir*1088 + n0l)*272;
  const int tr = tid & 15, tc = tid >> 4;
  const int lr = tid >> 2, lk = (tid & 3) << 2;
  const float ivr = invr[m0 + lr];
  const float* xrow = xb + (size_t)(m0 + lr)*272;
  const float* wrow = wb + (size_t)lr*272;
  float acc[4][4];
#pragma unroll
  for (int i=0;i<4;i++)
#pragma unroll
    for (int j=0;j<4;j++) acc[i][j]=0.f;
  for (int k0=0;k0<272;k0+=16){
    float4 a4 = *(const float4*)(xrow + k0 + lk);
    float4 g4 = *(const float4*)(n1w + k0 + lk);
    float4 b4 = *(const float4*)(wrow + k0 + lk);
    As[lk+0][lr] = a4.x*ivr*g4.x;
    As[lk+1][lr] = a4.y*ivr*g4.y;
    As[lk+2][lr] = a4.z*ivr*g4.z;
    As[lk+3][lr] = a4.w*ivr*g4.w;
    Bs[lk+0][lr] = b4.x; Bs[lk+1][lr]=b4.y; Bs[lk+2][lr]=b4.z; Bs[lk+3][lr]=b4.w;
    __syncthreads();
#pragma unroll
    for (int kk=0;kk<16;kk++){
      float4 av = *(const float4*)(&As[kk][tr<<2]);
      float4 bv = *(const float4*)(&Bs[kk][tc<<2]);
      acc[0][0]+=av.x*bv.x; acc[0][1]+=av.x*bv.y; acc[0][2]+=av.x*bv.z; acc[0][3]+=av.x*bv.w;
      acc[1][0]+=av.y*bv.x; acc[1][1]+=av.y*bv.y; acc[1][2]+=av.y*bv.z; acc[1][3]+=av.y*bv.w;
      acc[2][0]+=av.z*bv.x; acc[2][1]+=av.z*bv.y; acc[2][2]+=av.z*bv.z; acc[2][3]+=av.z*bv.w;
      acc[3][0]+=av.w*bv.x; acc[3][1]+=av.w*bv.y; acc[3][2]+=av.w*bv.z; acc[3][3]+=av.w*bv.w;
    }
    __syncthreads();
  }
#pragma unroll
  for (int i=0;i<4;i++){
    int r = m0 + (tr<<2) + i;
    int b = r >> 9, t = r & 511;
    int ts = dir ? (511 - t) : t;
    float4 v = make_float4(acc[i][0],acc[i][1],acc[i][2],acc[i][3]);
    *(float4*)(xz + (size_t)((dir*NB + b)*SEQL + ts)*DXZ + n0l + (tc<<2)) = v;
  }
}

// ---------------------------------------------------------------- conv4+silu, x_proj, dt_proj
__global__ __launch_bounds__(256) void k_convproj(
  const float* __restrict__ xz, const float* __restrict__ cwl, const float* __restrict__ cbl,
  const float* __restrict__ xwl, const float* __restrict__ dtwl, const float* __restrict__ dtbl,
  float* __restrict__ xcg, float* __restrict__ dtg, float* __restrict__ Bmg, float* __restrict__ Cmg)
{
  __shared__ float xcs[8][545];
  __shared__ float dts[8][20];
  const int tid = threadIdx.x;
  const int t0 = blockIdx.x << 3;
  const int b = blockIdx.y, dir = blockIdx.z;
  const size_t rb = (size_t)(dir*NB + b)*SEQL;
  const float* xzb = xz + rb*DXZ;
  const float* cw  = cwl + dir*DI*4;
  const float* cb  = cbl + dir*DI;
  const float* xw  = xwl + (size_t)dir*81*DI;
  const float* dtw = dtwl + dir*DI*DTR;
  const float* dtb = dtbl + dir*DI;

  for (int j=tid; j<DI; j+=256){
    float4 w4 = *(const float4*)(cw + j*4);
    float bj = cb[j];
#pragma unroll
    for (int ta=0; ta<8; ta++){
      int t = t0+ta;
      float acc = bj;
      if (t>=3){
        acc += w4.x*xzb[(size_t)(t-3)*DXZ+j];
        acc += w4.y*xzb[(size_t)(t-2)*DXZ+j];
        acc += w4.z*xzb[(size_t)(t-1)*DXZ+j];
        acc += w4.w*xzb[(size_t)t*DXZ+j];
      } else {
        const float* wp = &w4.x;
        for (int k=0;k<4;k++){ int tt=t-3+k; if(tt>=0) acc += wp[k]*xzb[(size_t)tt*DXZ+j]; }
      }
      float v = acc * sigmoid_fast(acc);
      xcs[ta][j] = v;
      xcg[(rb + t)*DI + j] = v;
    }
  }
  __syncthreads();
  {
    const int g = tid>>3, l8 = tid&7;
    const int j0 = l8*68;
    for (int idx=g; idx<648; idx+=32){
      int ta = idx/81, e = idx - ta*81;
      const float* wr = xw + (size_t)e*DI + j0;
      const float* xr = &xcs[ta][j0];
      float s = 0.f;
#pragma unroll 4
      for (int j=0;j<68;j++) s += wr[j]*xr[j];
      s += __shfl_xor(s,1); s += __shfl_xor(s,2); s += __shfl_xor(s,4);
      if (l8==0){
        if (e < DTR)          dts[ta][e] = s;
        else if (e < DTR+DS)  Bmg[(rb + t0+ta)*DS + (e-DTR)] = s;
        else                  Cmg[(rb + t0+ta)*DS + (e-DTR-DS)] = s;
      }
    }
  }
  __syncthreads();
  for (int d=tid; d<DI; d+=256){
    float w[DTR];
#pragma unroll
    for (int r=0;r<DTR;r++) w[r] = dtw[d*DTR + r];
    float bd = dtb[d];
#pragma unroll
    for (int ta=0;ta<8;ta++){
      float acc = bd;
#pragma unroll
      for (int r=0;r<DTR;r++) acc += w[r]*dts[ta][r];
      float sp = (acc > 20.f) ? acc : log1pf(__expf(acc));
      dtg[(rb+t0+ta)*DI + d] = sp;
    }
  }
}

// ---------------------------------------------------------------- chunked selective scan + gate
// block per (d, b, dir): 16 chunks x 8 state-groups(4 states) = 128 threads
__global__ __launch_bounds__(128) void k_scan(
  const float* __restrict__ dtg, const float* __restrict__ xcg,
  const float* __restrict__ Bmg, const float* __restrict__ Cmg,
  const float* __restrict__ alogl, const float* __restrict__ dskl,
  const float* __restrict__ xz, float* __restrict__ yog)
{
  __shared__ float hl[16][33], pl[16][33], Hi[16][33];
  const int d = blockIdx.x, b = blockIdx.y, dir = blockIdx.z;
  const int tid = threadIdx.x;
  const int c = tid >> 3, sg = tid & 7, s0 = sg << 2;
  float A0,A1,A2,A3;
  {
    const float* al = alogl + (size_t)(dir*DI + d)*DS + s0;
    A0 = -expf(al[0]); A1 = -expf(al[1]); A2 = -expf(al[2]); A3 = -expf(al[3]);
  }
  const size_t rb = (size_t)(dir*NB + b)*SEQL;
  const float* dtp = dtg + rb*DI + d;
  const float* xcp = xcg + rb*DI + d;
  const float* Bp  = Bmg + rb*DS + s0;
  const float* Cp  = Cmg + rb*DS + s0;
  float h0=0,h1=0,h2=0,h3=0,p0=1,p1=1,p2=1,p3=1;
  const int tb = c << 5;
  for (int ta=0; ta<32; ta++){
    int t = tb + ta;
    float ldt = dtp[(size_t)t*DI];
    float lxc = xcp[(size_t)t*DI];
    float4 B4 = *(const float4*)(Bp + (size_t)t*DS);
    float u = ldt*lxc;
    float e;
    e = __expf(ldt*A0); h0 = fmaf(e,h0,u*B4.x); p0*=e;
    e = __expf(ldt*A1); h1 = fmaf(e,h1,u*B4.y); p1*=e;
    e = __expf(ldt*A2); h2 = fmaf(e,h2,u*B4.z); p2*=e;
    e = __expf(ldt*A3); h3 = fmaf(e,h3,u*B4.w); p3*=e;
  }
  hl[c][s0]=h0; hl[c][s0+1]=h1; hl[c][s0+2]=h2; hl[c][s0+3]=h3;
  pl[c][s0]=p0; pl[c][s0+1]=p1; pl[c][s0+2]=p2; pl[c][s0+3]=p3;
  __syncthreads();
  if (tid < 32){
    float H = 0.f;
    Hi[0][tid] = 0.f;
    for (int cc=1; cc<16; cc++){
      H = fmaf(pl[cc-1][tid], H, hl[cc-1][tid]);
      Hi[cc][tid] = H;
    }
  }
  __syncthreads();
  h0=Hi[c][s0]; h1=Hi[c][s0+1]; h2=Hi[c][s0+2]; h3=Hi[c][s0+3];
  const float dsk = dskl[dir*DI + d];
  const float* zp = xz + rb*DXZ + DI + d;
  float* yop = yog + rb*DI + d;
  for (int ta=0; ta<32; ta++){
    int t = tb + ta;
    float ldt = dtp[(size_t)t*DI];
    float lxc = xcp[(size_t)t*DI];
    float4 B4 = *(const float4*)(Bp + (size_t)t*DS);
    float4 C4 = *(const float4*)(Cp + (size_t)t*DS);
    float u = ldt*lxc;
    float e;
    e = __expf(ldt*A0); h0 = fmaf(e,h0,u*B4.x);
    e = __expf(ldt*A1); h1 = fmaf(e,h1,u*B4.y);
    e = __expf(ldt*A2); h2 = fmaf(e,h2,u*B4.z);
    e = __expf(ldt*A3); h3 = fmaf(e,h3,u*B4.w);
    float y = h0*C4.x + h1*C4.y + h2*C4.z + h3*C4.w;
    y += __shfl_xor(y,1); y += __shfl_xor(y,2); y += __shfl_xor(y,4);
    if (sg==0){
      float z = zp[(size_t)t*DXZ];
      yop[(size_t)t*DI] = fmaf(dsk, lxc, y) * (z * sigmoid_fast(z));
    }
  }
}

// ---------------------------------------------------------------- out_proj GEMM (per dir, 64x32 tiles)
__global__ __launch_bounds__(128) void k_outproj(
    const float* __restrict__ yo, const float* __restrict__ ow, float* __restrict__ y12)
{
  __shared__ float As[16][76];
  __shared__ float Bs[16][40];
  const int tid = threadIdx.x;
  const int m0 = blockIdx.x << 6;
  const int n0 = blockIdx.y << 5;
  const int dir = blockIdx.z;
  const float* A = yo + (size_t)dir*ROWS*DI;
  const float* W = ow + (size_t)dir*DM*DI;
  const int lr = tid >> 1, lk8 = (tid & 1) << 3;
  const int lrb = tid >> 2, lkb = (tid & 3) << 2;
  const int tr = tid & 15, tc = tid >> 4;     // tc 0..7
  const float* arow = A + (size_t)(m0 + lr)*DI;
  const int nb = n0 + lrb;
  const bool bvalid = nb < DM;
  const float* wrow = W + (size_t)(bvalid ? nb : 0)*DI;
  float acc[4][4];
#pragma unroll
  for (int i=0;i<4;i++)
#pragma unroll
    for (int j=0;j<4;j++) acc[i][j]=0.f;
  for (int k0=0;k0<544;k0+=16){
    float4 a0 = *(const float4*)(arow + k0 + lk8);
    float4 a1 = *(const float4*)(arow + k0 + lk8 + 4);
    As[lk8+0][lr]=a0.x; As[lk8+1][lr]=a0.y; As[lk8+2][lr]=a0.z; As[lk8+3][lr]=a0.w;
    As[lk8+4][lr]=a1.x; As[lk8+5][lr]=a1.y; As[lk8+6][lr]=a1.z; As[lk8+7][lr]=a1.w;
    float4 b4 = bvalid ? *(const float4*)(wrow + k0 + lkb) : make_float4(0.f,0.f,0.f,0.f);
    Bs[lkb+0][lrb]=b4.x; Bs[lkb+1][lrb]=b4.y; Bs[lkb+2][lrb]=b4.z; Bs[lkb+3][lrb]=b4.w;
    __syncthreads();
#pragma unroll
    for (int kk=0;kk<16;kk++){
      float4 av = *(const float4*)(&As[kk][tr<<2]);
      float4 bv = *(const float4*)(&Bs[kk][tc<<2]);
      acc[0][0]+=av.x*bv.x; acc[0][1]+=av.x*bv.y; acc[0][2]+=av.x*bv.z; acc[0][3]+=av.x*bv.w;
      acc[1][0]+=av.y*bv.x; acc[1][1]+=av.y*bv.y; acc[1][2]+=av.y*bv.z; acc[1][3]+=av.y*bv.w;
      acc[2][0]+=av.z*bv.x; acc[2][1]+=av.z*bv.y; acc[2][2]+=av.z*bv.z; acc[2][3]+=av.z*bv.w;
      acc[3][0]+=av.w*bv.x; acc[3][1]+=av.w*bv.y; acc[3][2]+=av.w*bv.z; acc[3][3]+=av.w*bv.w;
    }
    __syncthreads();
  }
  int col = n0 + (tc<<2);
  if (col < DM){
#pragma unroll
    for (int i=0;i<4;i++){
      int r = m0 + (tr<<2) + i;
      int b = r >> 9, t = r & 511;
      int ts = dir ? (511 - t) : t;
      float4 v = make_float4(acc[i][0],acc[i][1],acc[i][2],acc[i][3]);
      *(float4*)(y12 + (size_t)dir*ROWS*DM + (size_t)(b*SEQL+ts)*DM + col) = v;
    }
  }
}

// ---------------------------------------------------------------- combine: lam, rmsnorm, residual
__global__ __launch_bounds__(256) void k_combine(
  const float* __restrict__ y12, const float* __restrict__ lamq,
  const float* __restrict__ n2w, float* __restrict__ xb,
  float* __restrict__ invr, float lam_init, float omli)
{
  __shared__ float sred[4];
  const int tid = threadIdx.x;
  const int r = blockIdx.x;
  const float* y1 = y12 + (size_t)r*DM;
  const float* y2 = y12 + (size_t)ROWS*DM + (size_t)r*DM;
  float lp = lamq[tid];
  if (tid < 16) lp += lamq[tid+256];
  float lsum = block_reduce_256(lp, sred, tid);
  float lam = sigmoid_fast(lsum) + lam_init;
  float a0 = y1[tid] - lam*y2[tid];
  float a1 = 0.f;
  if (tid<16) a1 = y1[tid+256] - lam*y2[tid+256];
  float ss = block_reduce_256(a0*a0 + a1*a1, sred, tid);
  float rms = rsqrtf(ss*(1.f/DM) + 1e-5f);
  float xo0 = xb[(size_t)r*DM + tid] + a0*rms*n2w[tid]*omli;
  float xo1 = 0.f;
  if (tid<16) xo1 = xb[(size_t)r*DM + tid+256] + a1*rms*n2w[tid+256]*omli;
  xb[(size_t)r*DM+tid] = xo0;
  if (tid<16) xb[(size_t)r*DM+tid+256] = xo1;
  float ss2 = block_reduce_256(xo0*xo0 + xo1*xo1, sred, tid);
  if (tid==0) invr[r] = rsqrtf(ss2*(1.f/DM) + 1e-5f);
}

// ---------------------------------------------------------------- head
__global__ __launch_bounds__(256) void k_head1(const float* __restrict__ xb, float* __restrict__ xmp){
  int ch = blockIdx.x, b = blockIdx.y, tid = threadIdx.x;
  int t0 = ch*64;
  float s0=0.f, s1=0.f;
  for (int t=t0; t<t0+64; t++){
    const float* row = xb + (size_t)(b*SEQL+t)*DM;
    s0 += row[tid];
    if (tid<16) s1 += row[tid+256];
  }
  xmp[(size_t)(b*8+ch)*DM + tid] = s0;
  if (tid<16) xmp[(size_t)(b*8+ch)*DM + tid+256] = s1;
}

__global__ __launch_bounds__(256) void k_head2(
  const float* __restrict__ xmp, const float* __restrict__ yin,
  const float* __restrict__ mlpw, const float* __restrict__ mlpb,
  const float* __restrict__ pw, const float* __restrict__ pb,
  float* __restrict__ out)
{
  __shared__ float xm[2][DM];
  __shared__ float x2s[2][DM];
  __shared__ float sred[4];
  int tid = threadIdx.x;
  for (int idx=tid; idx<2*DM; idx+=256){
    int b = idx / DM, c = idx - b*DM;
    float s=0.f;
    for (int ch=0; ch<8; ch++) s += xmp[(size_t)(b*8+ch)*DM + c];
    xm[b][c] = s * (1.f/SEQL);
  }
  __syncthreads();
  for (int idx=tid; idx<2*DM; idx+=256){
    int b = idx / DM, c = idx - b*DM;
    float acc = mlpb[c];
    const float* wr = mlpw + (size_t)c*DM;
    for (int k=0;k<DM;k++) acc += wr[k]*xm[b][k];
    float v = fmaxf(acc, 0.f);
    x2s[b][c] = v;
    out[2 + b*DM + c] = v;
  }
  __syncthreads();
  for (int b=0;b<2;b++){
    float p = x2s[b][tid]*pw[tid];
    if (tid<16) p += x2s[b][tid+256]*pw[tid+256];
    float tot = block_reduce_256(p, sred, tid);
    if (tid==0) out[b] = tot + yin[b]*pw[DM] + pb[0];
  }
}

// ----------------------------------------------------------------
extern "C" void kernel_launch(void* const* d_in, const int* in_sizes, int n_in,
                              void* d_out, int out_size, void* d_ws, size_t ws_size,
                              hipStream_t stream)
{
  const float* x0     = (const float*)d_in[0];
  const float* yin    = (const float*)d_in[1];
  const float* in_w   = (const float*)d_in[2];
  const float* conv_w = (const float*)d_in[3];
  const float* conv_b = (const float*)d_in[4];
  const float* x_w    = (const float*)d_in[5];
  const float* dt_w   = (const float*)d_in[6];
  const float* dt_b   = (const float*)d_in[7];
  const float* a_log  = (const float*)d_in[8];
  const float* dskip  = (const float*)d_in[9];
  const float* out_w  = (const float*)d_in[10];
  const float* lamq   = (const float*)d_in[11];
  const float* n1w    = (const float*)d_in[12];
  const float* n2w    = (const float*)d_in[13];
  const float* mlpw   = (const float*)d_in[14];
  const float* mlpb   = (const float*)d_in[15];
  const float* pw     = (const float*)d_in[16];
  const float* pb     = (const float*)d_in[17];

  float* ws  = (float*)d_ws;
  float* xb  = ws + OFF_X;
  float* invr= ws + OFF_INVR;
  float* xz  = ws + OFF_XZ;
  float* xc  = ws + OFF_XC;
  float* dt  = ws + OFF_DT;
  float* Bm  = ws + OFF_BM;
  float* Cm  = ws + OFF_CM;
  float* yo  = ws + OFF_YO;
  float* y12 = ws + OFF_Y12;
  float* xmp = ws + OFF_XMP;
  float* outp = (float*)d_out;

  k_init<<<ROWS, 64, 0, stream>>>(x0, xb, invr);
  for (int i=0;i<NL;i++){
    float lam_init = 0.8f - 0.6f*expf(-0.3f*(float)i);
    k_inproj<<<dim3(16,34), 256, 0, stream>>>(xb, invr, n1w + (size_t)i*DM,
        in_w + (size_t)i*2*DXZ/2*2*272, xz); // i*2*1088*272
    k_convproj<<<dim3(64,2,2), 256, 0, stream>>>(xz,
        conv_w + (size_t)i*2*DI*4, conv_b + (size_t)i*2*DI,
        x_w + (size_t)i*2*81*DI, dt_w + (size_t)i*2*DI*DTR, dt_b + (size_t)i*2*DI,
        xc, dt, Bm, Cm);
    k_scan<<<dim3(DI,NB,2), 128, 0, stream>>>(dt, xc, Bm, Cm,
        a_log + (size_t)i*2*DI*DS, dskip + (size_t)i*2*DI, xz, yo);
    k_outproj<<<dim3(16,9,2), 128, 0, stream>>>(yo, out_w + (size_t)i*2*DM*DI, y12);
    k_combine<<<ROWS, 256, 0, stream>>>(y12, lamq + (size_t)i*DM, n2w + (size_t)i*DM,
        xb, invr, lam_init, 1.f - lam_init);
  }
  k_head1<<<dim3(8,2), 256, 0, stream>>>(xb, xmp);
  k_head2<<<1, 256, 0, stream>>>(xmp, yin, mlpw, mlpb, pw, pb, outp);
}

// Round 2
// 2300.129 us; speedup vs baseline: 1.1662x; 1.1662x over previous
//
#include <hip/hip_runtime.h>
#include <math.h>

#define DM   272
#define DS   32
#define DI   544
#define DTR  17
#define SEQL 512
#define NB   2
#define ROWS 1024
#define DXZ  1088
#define NL   12

// workspace offsets (in floats)
#define OFF_X     0          // 1024*272
#define OFF_INVR  278528     // 1024
#define OFF_XZ    279552     // 2*2*512*1088
#define OFF_XC    2507776    // 2*2*512*544
#define OFF_DT    3621888    // 2*2*512*544
#define OFF_BM    4736000    // 2*2*512*32
#define OFF_CM    4801536    // 2*2*512*32
#define OFF_YO    4867072    // 2*2*512*544
#define OFF_Y12   5981184    // 2*1024*272
#define OFF_XMP   6538240    // 16*272
#define OFF_XWT   6542592    // 24*544*81  = 1,057,536
#define OFF_DTWT  7600128    // 24*17*544  =   221,952
// end: 7,822,080 floats = 31.3 MB

__device__ __forceinline__ float sigmoid_fast(float x){ return 1.f/(1.f+__expf(-x)); }
__device__ __forceinline__ float softplus_f(float x){ return (x > 20.f) ? x : log1pf(__expf(x)); }

__device__ __forceinline__ float block_reduce_256(float v, volatile float* sred, int tid){
#pragma unroll
  for (int m=32; m>=1; m>>=1) v += __shfl_xor(v, m);
  __syncthreads();
  if ((tid & 63) == 0) sred[tid>>6] = v;
  __syncthreads();
  return sred[0]+sred[1]+sred[2]+sred[3];
}

// ---------------------------------------------------------------- init: copy x, per-row invrms
__global__ __launch_bounds__(64) void k_init(const float* __restrict__ x0,
                                             float* __restrict__ xb, float* __restrict__ invr){
  int r = blockIdx.x, tid = threadIdx.x;
  float ss = 0.f;
  for (int c=tid; c<DM; c+=64){ float v = x0[(size_t)r*DM+c]; xb[(size_t)r*DM+c]=v; ss += v*v; }
#pragma unroll
  for (int m=32;m>=1;m>>=1) ss += __shfl_xor(ss,m);
  if (tid==0) invr[r] = rsqrtf(ss*(1.f/DM)+1e-5f);
}

// ---------------------------------------------------------------- weight transposes (once per call)
// xw [24][81][544] -> xwT [24][544][81] ; dtw [24][544][17] -> dtwT [24][17][544]
__global__ __launch_bounds__(256) void k_transpose(const float* __restrict__ xw,
                                                   const float* __restrict__ dtw,
                                                   float* __restrict__ xwT,
                                                   float* __restrict__ dtwT){
  int idx = blockIdx.x*256 + threadIdx.x;
  const int T1 = 24*81*544;
  const int T2 = 24*544*DTR;
  if (idx < T1){
    int ld = idx / (81*544); int rem = idx - ld*(81*544);
    int e = rem / 544; int k = rem - e*544;
    xwT[(size_t)ld*544*81 + (size_t)k*81 + e] = xw[idx];
  } else if (idx < T1 + T2){
    int j = idx - T1;
    int ld = j / (544*DTR); int rem = j - ld*(544*DTR);
    int d = rem / DTR; int r = rem - d*DTR;
    dtwT[(size_t)ld*DTR*544 + (size_t)r*544 + d] = dtw[j];
  }
}

// ---------------------------------------------------------------- in_proj GEMM (rmsnorm fused)
// C[1024 x 2176] = xn[1024 x 272] @ W^T ; dir1 rows stored time-flipped
__global__ __launch_bounds__(256) void k_inproj(
    const float* __restrict__ xb, const float* __restrict__ invr,
    const float* __restrict__ n1w, const float* __restrict__ inw,
    float* __restrict__ xz)
{
  __shared__ float As[16][76];
  __shared__ float Bs[16][76];
  const int tid = threadIdx.x;
  const int m0 = blockIdx.x << 6;
  const int nt = blockIdx.y;                    // 0..33
  const int dir = (nt >= 17) ? 1 : 0;
  const int n0l = (nt - dir*17) << 6;           // local col within dir
  const float* wb = inw + (size_t)(dir*1088 + n0l)*272;
  const int tr = tid & 15, tc = tid >> 4;
  const int lr = tid >> 2, lk = (tid & 3) << 2;
  const float ivr = invr[m0 + lr];
  const float* xrow = xb + (size_t)(m0 + lr)*272;
  const float* wrow = wb + (size_t)lr*272;
  float acc[4][4];
#pragma unroll
  for (int i=0;i<4;i++)
#pragma unroll
    for (int j=0;j<4;j++) acc[i][j]=0.f;
  for (int k0=0;k0<272;k0+=16){
    float4 a4 = *(const float4*)(xrow + k0 + lk);
    float4 g4 = *(const float4*)(n1w + k0 + lk);
    float4 b4 = *(const float4*)(wrow + k0 + lk);
    As[lk+0][lr] = a4.x*ivr*g4.x;
    As[lk+1][lr] = a4.y*ivr*g4.y;
    As[lk+2][lr] = a4.z*ivr*g4.z;
    As[lk+3][lr] = a4.w*ivr*g4.w;
    Bs[lk+0][lr] = b4.x; Bs[lk+1][lr]=b4.y; Bs[lk+2][lr]=b4.z; Bs[lk+3][lr]=b4.w;
    __syncthreads();
#pragma unroll
    for (int kk=0;kk<16;kk++){
      float4 av = *(const float4*)(&As[kk][tr<<2]);
      float4 bv = *(const float4*)(&Bs[kk][tc<<2]);
      acc[0][0]+=av.x*bv.x; acc[0][1]+=av.x*bv.y; acc[0][2]+=av.x*bv.z; acc[0][3]+=av.x*bv.w;
      acc[1][0]+=av.y*bv.x; acc[1][1]+=av.y*bv.y; acc[1][2]+=av.y*bv.z; acc[1][3]+=av.y*bv.w;
      acc[2][0]+=av.z*bv.x; acc[2][1]+=av.z*bv.y; acc[2][2]+=av.z*bv.z; acc[2][3]+=av.z*bv.w;
      acc[3][0]+=av.w*bv.x; acc[3][1]+=av.w*bv.y; acc[3][2]+=av.w*bv.z; acc[3][3]+=av.w*bv.w;
    }
    __syncthreads();
  }
#pragma unroll
  for (int i=0;i<4;i++){
    int r = m0 + (tr<<2) + i;
    int b = r >> 9, t = r & 511;
    int ts = dir ? (511 - t) : t;
    float4 v = make_float4(acc[i][0],acc[i][1],acc[i][2],acc[i][3]);
    *(float4*)(xz + (size_t)((dir*NB + b)*SEQL + ts)*DXZ + n0l + (tc<<2)) = v;
  }
}

// ---------------------------------------------------------------- conv4+silu + x_proj + dt_proj
// block = 256 threads, 4 consecutive rows. thread-per-output dots, coalesced transposed weights.
__global__ __launch_bounds__(256) void k_xdt(
  const float* __restrict__ xz, const float* __restrict__ cwl, const float* __restrict__ cbl,
  const float* __restrict__ xwTl, const float* __restrict__ dtwTl, const float* __restrict__ dtbl,
  float* __restrict__ xcg, float* __restrict__ dtg, float* __restrict__ Bmg, float* __restrict__ Cmg)
{
  __shared__ float xcs[4][545];
  __shared__ float dts[4][DTR];
  const int tid = threadIdx.x;
  const int r0 = blockIdx.x << 2;            // global row, 4 per block
  const int dir = r0 >> 10;
  const int t0 = r0 & 511;
  const size_t rb = (size_t)(r0 - t0);       // segment base row
  const float* xzb  = xz + rb*DXZ;
  const float* cw   = cwl + dir*DI*4;
  const float* cb   = cbl + dir*DI;
  const float* xwT  = xwTl + (size_t)dir*DI*81;
  const float* dtwT = dtwTl + (size_t)dir*DTR*DI;
  const float* dtb  = dtbl + dir*DI;

  // phase 1: conv4 + silu
  for (int j = tid; j < DI; j += 256){
    float4 w4 = *(const float4*)(cw + j*4);
    float bj = cb[j];
#pragma unroll
    for (int rr=0; rr<4; rr++){
      int t = t0 + rr;
      float x3 = (t>=3) ? xzb[(size_t)(t-3)*DXZ + j] : 0.f;
      float x2 = (t>=2) ? xzb[(size_t)(t-2)*DXZ + j] : 0.f;
      float x1 = (t>=1) ? xzb[(size_t)(t-1)*DXZ + j] : 0.f;
      float x0v = xzb[(size_t)t*DXZ + j];
      float acc = bj + w4.x*x3 + w4.y*x2 + w4.z*x1 + w4.w*x0v;
      float v = acc * sigmoid_fast(acc);
      xcs[rr][j] = v;
      xcg[(rb + t)*DI + j] = v;
    }
  }
  __syncthreads();

  // phase 2: x_proj — thread owns full length-544 dot(s)
  {
    const int l = tid & 31, rg = tid >> 5;
    const int r = rg & 3, h = rg >> 2;
    const int e = h*32 + l;
    const bool has2 = (h==0) && (l < DTR);
    const int e2 = 64 + l;
    float acc = 0.f, acc2 = 0.f;
    const float* xr = xcs[r];
    for (int k=0; k<DI; k+=4){
      float x0 = xr[k], x1 = xr[k+1], x2 = xr[k+2], x3 = xr[k+3];
      const float* wp = xwT + (size_t)k*81;
      acc += x0*wp[e] + x1*wp[81+e] + x2*wp[162+e] + x3*wp[243+e];
      if (has2) acc2 += x0*wp[e2] + x1*wp[81+e2] + x2*wp[162+e2] + x3*wp[243+e2];
    }
    const size_t row = (size_t)(r0 + r);
    if (e < DTR)           dts[r][e] = acc;
    else if (e < DTR+DS)   Bmg[row*DS + (e-DTR)] = acc;
    else                   Cmg[row*DS + (e-49)] = acc;
    if (has2)              Cmg[row*DS + (e2-49)] = acc2;
  }
  __syncthreads();

  // phase 3: dt_proj + softplus; cols tid, tid+256, (tid<32: 512+tid)
  {
    float w1[DTR], w2[DTR], w3[DTR];
    const int c1 = tid, c2 = tid+256;
    const bool h3 = tid < 32; const int c3 = 512 + tid;
#pragma unroll
    for (int q=0; q<DTR; q++){
      w1[q] = dtwT[q*DI + c1];
      w2[q] = dtwT[q*DI + c2];
      w3[q] = h3 ? dtwT[q*DI + c3] : 0.f;
    }
    float b1 = dtb[c1], b2 = dtb[c2], b3 = h3 ? dtb[c3] : 0.f;
#pragma unroll
    for (int rr=0; rr<4; rr++){
      float a1=b1, a2=b2, a3=b3;
#pragma unroll
      for (int q=0; q<DTR; q++){
        float dv = dts[rr][q];
        a1 += w1[q]*dv; a2 += w2[q]*dv; a3 += w3[q]*dv;
      }
      size_t ro = (size_t)(r0 + rr)*DI;
      dtg[ro + c1] = softplus_f(a1);
      dtg[ro + c2] = softplus_f(a2);
      if (h3) dtg[ro + c3] = softplus_f(a3);
    }
  }
}

// ---------------------------------------------------------------- chunked selective scan + gate
__global__ __launch_bounds__(128) void k_scan(
  const float* __restrict__ dtg, const float* __restrict__ xcg,
  const float* __restrict__ Bmg, const float* __restrict__ Cmg,
  const float* __restrict__ alogl, const float* __restrict__ dskl,
  const float* __restrict__ xz, float* __restrict__ yog)
{
  __shared__ float hl[16][33], pl[16][33], Hi[16][33];
  const int d = blockIdx.x, b = blockIdx.y, dir = blockIdx.z;
  const int tid = threadIdx.x;
  const int c = tid >> 3, sg = tid & 7, s0 = sg << 2;
  float A0,A1,A2,A3;
  {
    const float* al = alogl + (size_t)(dir*DI + d)*DS + s0;
    A0 = -expf(al[0]); A1 = -expf(al[1]); A2 = -expf(al[2]); A3 = -expf(al[3]);
  }
  const size_t rb = (size_t)(dir*NB + b)*SEQL;
  const float* dtp = dtg + rb*DI + d;
  const float* xcp = xcg + rb*DI + d;
  const float* Bp  = Bmg + rb*DS + s0;
  const float* Cp  = Cmg + rb*DS + s0;
  float h0=0,h1=0,h2=0,h3=0,p0=1,p1=1,p2=1,p3=1;
  const int tb = c << 5;
  for (int ta=0; ta<32; ta++){
    int t = tb + ta;
    float ldt = dtp[(size_t)t*DI];
    float lxc = xcp[(size_t)t*DI];
    float4 B4 = *(const float4*)(Bp + (size_t)t*DS);
    float u = ldt*lxc;
    float e;
    e = __expf(ldt*A0); h0 = fmaf(e,h0,u*B4.x); p0*=e;
    e = __expf(ldt*A1); h1 = fmaf(e,h1,u*B4.y); p1*=e;
    e = __expf(ldt*A2); h2 = fmaf(e,h2,u*B4.z); p2*=e;
    e = __expf(ldt*A3); h3 = fmaf(e,h3,u*B4.w); p3*=e;
  }
  hl[c][s0]=h0; hl[c][s0+1]=h1; hl[c][s0+2]=h2; hl[c][s0+3]=h3;
  pl[c][s0]=p0; pl[c][s0+1]=p1; pl[c][s0+2]=p2; pl[c][s0+3]=p3;
  __syncthreads();
  if (tid < 32){
    float H = 0.f;
    Hi[0][tid] = 0.f;
    for (int cc=1; cc<16; cc++){
      H = fmaf(pl[cc-1][tid], H, hl[cc-1][tid]);
      Hi[cc][tid] = H;
    }
  }
  __syncthreads();
  h0=Hi[c][s0]; h1=Hi[c][s0+1]; h2=Hi[c][s0+2]; h3=Hi[c][s0+3];
  const float dsk = dskl[dir*DI + d];
  const float* zp = xz + rb*DXZ + DI + d;
  float* yop = yog + rb*DI + d;
  for (int ta=0; ta<32; ta++){
    int t = tb + ta;
    float ldt = dtp[(size_t)t*DI];
    float lxc = xcp[(size_t)t*DI];
    float4 B4 = *(const float4*)(Bp + (size_t)t*DS);
    float4 C4 = *(const float4*)(Cp + (size_t)t*DS);
    float u = ldt*lxc;
    float e;
    e = __expf(ldt*A0); h0 = fmaf(e,h0,u*B4.x);
    e = __expf(ldt*A1); h1 = fmaf(e,h1,u*B4.y);
    e = __expf(ldt*A2); h2 = fmaf(e,h2,u*B4.z);
    e = __expf(ldt*A3); h3 = fmaf(e,h3,u*B4.w);
    float y = h0*C4.x + h1*C4.y + h2*C4.z + h3*C4.w;
    y += __shfl_xor(y,1); y += __shfl_xor(y,2); y += __shfl_xor(y,4);
    if (sg==0){
      float z = zp[(size_t)t*DXZ];
      yop[(size_t)t*DI] = fmaf(dsk, lxc, y) * (z * sigmoid_fast(z));
    }
  }
}

// ---------------------------------------------------------------- out_proj GEMM (per dir, 64x32 tiles)
__global__ __launch_bounds__(128) void k_outproj(
    const float* __restrict__ yo, const float* __restrict__ ow, float* __restrict__ y12)
{
  __shared__ float As[16][76];
  __shared__ float Bs[16][40];
  const int tid = threadIdx.x;
  const int m0 = blockIdx.x << 6;
  const int n0 = blockIdx.y << 5;
  const int dir = blockIdx.z;
  const float* A = yo + (size_t)dir*ROWS*DI;
  const float* W = ow + (size_t)dir*DM*DI;
  const int lr = tid >> 1, lk8 = (tid & 1) << 3;
  const int lrb = tid >> 2, lkb = (tid & 3) << 2;
  const int tr = tid & 15, tc = tid >> 4;     // tc 0..7
  const float* arow = A + (size_t)(m0 + lr)*DI;
  const int nb = n0 + lrb;
  const bool bvalid = nb < DM;
  const float* wrow = W + (size_t)(bvalid ? nb : 0)*DI;
  float acc[4][4];
#pragma unroll
  for (int i=0;i<4;i++)
#pragma unroll
    for (int j=0;j<4;j++) acc[i][j]=0.f;
  for (int k0=0;k0<544;k0+=16){
    float4 a0 = *(const float4*)(arow + k0 + lk8);
    float4 a1 = *(const float4*)(arow + k0 + lk8 + 4);
    As[lk8+0][lr]=a0.x; As[lk8+1][lr]=a0.y; As[lk8+2][lr]=a0.z; As[lk8+3][lr]=a0.w;
    As[lk8+4][lr]=a1.x; As[lk8+5][lr]=a1.y; As[lk8+6][lr]=a1.z; As[lk8+7][lr]=a1.w;
    float4 b4 = bvalid ? *(const float4*)(wrow + k0 + lkb) : make_float4(0.f,0.f,0.f,0.f);
    Bs[lkb+0][lrb]=b4.x; Bs[lkb+1][lrb]=b4.y; Bs[lkb+2][lrb]=b4.z; Bs[lkb+3][lrb]=b4.w;
    __syncthreads();
#pragma unroll
    for (int kk=0;kk<16;kk++){
      float4 av = *(const float4*)(&As[kk][tr<<2]);
      float4 bv = *(const float4*)(&Bs[kk][tc<<2]);
      acc[0][0]+=av.x*bv.x; acc[0][1]+=av.x*bv.y; acc[0][2]+=av.x*bv.z; acc[0][3]+=av.x*bv.w;
      acc[1][0]+=av.y*bv.x; acc[1][1]+=av.y*bv.y; acc[1][2]+=av.y*bv.z; acc[1][3]+=av.y*bv.w;
      acc[2][0]+=av.z*bv.x; acc[2][1]+=av.z*bv.y; acc[2][2]+=av.z*bv.z; acc[2][3]+=av.z*bv.w;
      acc[3][0]+=av.w*bv.x; acc[3][1]+=av.w*bv.y; acc[3][2]+=av.w*bv.z; acc[3][3]+=av.w*bv.w;
    }
    __syncthreads();
  }
  int col = n0 + (tc<<2);
  if (col < DM){
#pragma unroll
    for (int i=0;i<4;i++){
      int r = m0 + (tr<<2) + i;
      int b = r >> 9, t = r & 511;
      int ts = dir ? (511 - t) : t;
      float4 v = make_float4(acc[i][0],acc[i][1],acc[i][2],acc[i][3]);
      *(float4*)(y12 + (size_t)dir*ROWS*DM + (size_t)(b*SEQL+ts)*DM + col) = v;
    }
  }
}

// ---------------------------------------------------------------- combine: lam, rmsnorm, residual
__global__ __launch_bounds__(256) void k_combine(
  const float* __restrict__ y12, const float* __restrict__ lamq,
  const float* __restrict__ n2w, float* __restrict__ xb,
  float* __restrict__ invr, float lam_init, float omli)
{
  __shared__ float sred[4];
  const int tid = threadIdx.x;
  const int r = blockIdx.x;
  const float* y1 = y12 + (size_t)r*DM;
  const float* y2 = y12 + (size_t)ROWS*DM + (size_t)r*DM;
  float lp = lamq[tid];
  if (tid < 16) lp += lamq[tid+256];
  float lsum = block_reduce_256(lp, sred, tid);
  float lam = sigmoid_fast(lsum) + lam_init;
  float a0 = y1[tid] - lam*y2[tid];
  float a1 = 0.f;
  if (tid<16) a1 = y1[tid+256] - lam*y2[tid+256];
  float ss = block_reduce_256(a0*a0 + a1*a1, sred, tid);
  float rms = rsqrtf(ss*(1.f/DM) + 1e-5f);
  float xo0 = xb[(size_t)r*DM + tid] + a0*rms*n2w[tid]*omli;
  float xo1 = 0.f;
  if (tid<16) xo1 = xb[(size_t)r*DM + tid+256] + a1*rms*n2w[tid+256]*omli;
  xb[(size_t)r*DM+tid] = xo0;
  if (tid<16) xb[(size_t)r*DM+tid+256] = xo1;
  float ss2 = block_reduce_256(xo0*xo0 + xo1*xo1, sred, tid);
  if (tid==0) invr[r] = rsqrtf(ss2*(1.f/DM) + 1e-5f);
}

// ---------------------------------------------------------------- head
__global__ __launch_bounds__(256) void k_head1(const float* __restrict__ xb, float* __restrict__ xmp){
  int ch = blockIdx.x, b = blockIdx.y, tid = threadIdx.x;
  int t0 = ch*64;
  float s0=0.f, s1=0.f;
  for (int t=t0; t<t0+64; t++){
    const float* row = xb + (size_t)(b*SEQL+t)*DM;
    s0 += row[tid];
    if (tid<16) s1 += row[tid+256];
  }
  xmp[(size_t)(b*8+ch)*DM + tid] = s0;
  if (tid<16) xmp[(size_t)(b*8+ch)*DM + tid+256] = s1;
}

__global__ __launch_bounds__(256) void k_head2(
  const float* __restrict__ xmp, const float* __restrict__ yin,
  const float* __restrict__ mlpw, const float* __restrict__ mlpb,
  const float* __restrict__ pw, const float* __restrict__ pb,
  float* __restrict__ out)
{
  __shared__ float xm[2][DM];
  __shared__ float x2s[2][DM];
  __shared__ float sred[4];
  int tid = threadIdx.x;
  for (int idx=tid; idx<2*DM; idx+=256){
    int b = idx / DM, c = idx - b*DM;
    float s=0.f;
    for (int ch=0; ch<8; ch++) s += xmp[(size_t)(b*8+ch)*DM + c];
    xm[b][c] = s * (1.f/SEQL);
  }
  __syncthreads();
  for (int idx=tid; idx<2*DM; idx+=256){
    int b = idx / DM, c = idx - b*DM;
    float acc = mlpb[c];
    const float* wr = mlpw + (size_t)c*DM;
    for (int k=0;k<DM;k++) acc += wr[k]*xm[b][k];
    float v = fmaxf(acc, 0.f);
    x2s[b][c] = v;
    out[2 + b*DM + c] = v;
  }
  __syncthreads();
  for (int b=0;b<2;b++){
    float p = x2s[b][tid]*pw[tid];
    if (tid<16) p += x2s[b][tid+256]*pw[tid+256];
    float tot = block_reduce_256(p, sred, tid);
    if (tid==0) out[b] = tot + yin[b]*pw[DM] + pb[0];
  }
}

// ----------------------------------------------------------------
extern "C" void kernel_launch(void* const* d_in, const int* in_sizes, int n_in,
                              void* d_out, int out_size, void* d_ws, size_t ws_size,
                              hipStream_t stream)
{
  const float* x0     = (const float*)d_in[0];
  const float* yin    = (const float*)d_in[1];
  const float* in_w   = (const float*)d_in[2];
  const float* conv_w = (const float*)d_in[3];
  const float* conv_b = (const float*)d_in[4];
  const float* x_w    = (const float*)d_in[5];
  const float* dt_w   = (const float*)d_in[6];
  const float* dt_b   = (const float*)d_in[7];
  const float* a_log  = (const float*)d_in[8];
  const float* dskip  = (const float*)d_in[9];
  const float* out_w  = (const float*)d_in[10];
  const float* lamq   = (const float*)d_in[11];
  const float* n1w    = (const float*)d_in[12];
  const float* n2w    = (const float*)d_in[13];
  const float* mlpw   = (const float*)d_in[14];
  const float* mlpb   = (const float*)d_in[15];
  const float* pw     = (const float*)d_in[16];
  const float* pb     = (const float*)d_in[17];

  float* ws  = (float*)d_ws;
  float* xb  = ws + OFF_X;
  float* invr= ws + OFF_INVR;
  float* xz  = ws + OFF_XZ;
  float* xc  = ws + OFF_XC;
  float* dt  = ws + OFF_DT;
  float* Bm  = ws + OFF_BM;
  float* Cm  = ws + OFF_CM;
  float* yo  = ws + OFF_YO;
  float* y12 = ws + OFF_Y12;
  float* xmp = ws + OFF_XMP;
  float* xwT = ws + OFF_XWT;
  float* dtwT= ws + OFF_DTWT;
  float* outp = (float*)d_out;

  k_transpose<<<(24*81*544 + 24*544*DTR + 255)/256, 256, 0, stream>>>(x_w, dt_w, xwT, dtwT);
  k_init<<<ROWS, 64, 0, stream>>>(x0, xb, invr);
  for (int i=0;i<NL;i++){
    float lam_init = 0.8f - 0.6f*expf(-0.3f*(float)i);
    k_inproj<<<dim3(16,34), 256, 0, stream>>>(xb, invr, n1w + (size_t)i*DM,
        in_w + (size_t)i*2176*272, xz);
    k_xdt<<<512, 256, 0, stream>>>(xz,
        conv_w + (size_t)i*2*DI*4, conv_b + (size_t)i*2*DI,
        xwT + (size_t)i*2*DI*81, dtwT + (size_t)i*2*DTR*DI, dt_b + (size_t)i*2*DI,
        xc, dt, Bm, Cm);
    k_scan<<<dim3(DI,NB,2), 128, 0, stream>>>(dt, xc, Bm, Cm,
        a_log + (size_t)i*2*DI*DS, dskip + (size_t)i*2*DI, xz, yo);
    k_outproj<<<dim3(16,9,2), 128, 0, stream>>>(yo, out_w + (size_t)i*2*DM*DI, y12);
    k_combine<<<ROWS, 256, 0, stream>>>(y12, lamq + (size_t)i*DM, n2w + (size_t)i*DM,
        xb, invr, lam_init, 1.f - lam_init);
  }
  k_head1<<<dim3(8,2), 256, 0, stream>>>(xb, xmp);
  k_head2<<<1, 256, 0, stream>>>(xmp, yin, mlpw, mlpb, pw, pb, outp);
}

// Round 3
// 1751.942 us; speedup vs baseline: 1.5310x; 1.3129x over previous
//
#include <hip/hip_runtime.h>
#include <math.h>

#define DM   272
#define DS   32
#define DI   544
#define DTR  17
#define SEQL 512
#define NB   2
#define ROWS 1024
#define DXZ  1088
#define NL   12

// workspace offsets (in floats)
#define OFF_X     0          // 1024*272
#define OFF_INVR  278528     // 1024
#define OFF_XZ    279552     // 4*512*1088 = 2228224
#define OFF_XCT   2507776    // 4*544*512  = 1114112  (channel-major)
#define OFF_DTT   3621888    // 4*544*512
#define OFF_ZT    4736000    // 4*544*512
#define OFF_BM    5850112    // 4*512*32 = 65536
#define OFF_CM    5915648    // 4*512*32
#define OFF_YOT   5981184    // 4*544*512  (channel-major)
#define OFF_Y12   7095296    // 2*1024*272 = 557056
#define OFF_XMP   7652352    // 16*272
#define OFF_XWT   7656704    // 24*544*81  = 1057536
#define OFF_DTWT  8714240    // 24*17*544  = 221952
// end: 8,936,192 floats = 35.7 MB

__device__ __forceinline__ float sigmoid_fast(float x){ return 1.f/(1.f+__expf(-x)); }
__device__ __forceinline__ float softplus_f(float x){ return (x > 20.f) ? x : log1pf(__expf(x)); }

__device__ __forceinline__ float block_reduce_256(float v, volatile float* sred, int tid){
#pragma unroll
  for (int m=32; m>=1; m>>=1) v += __shfl_xor(v, m);
  __syncthreads();
  if ((tid & 63) == 0) sred[tid>>6] = v;
  __syncthreads();
  return sred[0]+sred[1]+sred[2]+sred[3];
}

// ---------------------------------------------------------------- init
__global__ __launch_bounds__(64) void k_init(const float* __restrict__ x0,
                                             float* __restrict__ xb, float* __restrict__ invr){
  int r = blockIdx.x, tid = threadIdx.x;
  float ss = 0.f;
  for (int c=tid; c<DM; c+=64){ float v = x0[(size_t)r*DM+c]; xb[(size_t)r*DM+c]=v; ss += v*v; }
#pragma unroll
  for (int m=32;m>=1;m>>=1) ss += __shfl_xor(ss,m);
  if (tid==0) invr[r] = rsqrtf(ss*(1.f/DM)+1e-5f);
}

// ---------------------------------------------------------------- weight transposes (once per call)
__global__ __launch_bounds__(256) void k_transpose(const float* __restrict__ xw,
                                                   const float* __restrict__ dtw,
                                                   float* __restrict__ xwT,
                                                   float* __restrict__ dtwT){
  int idx = blockIdx.x*256 + threadIdx.x;
  const int T1 = 24*81*544;
  const int T2 = 24*544*DTR;
  if (idx < T1){
    int ld = idx / (81*544); int rem = idx - ld*(81*544);
    int e = rem / 544; int k = rem - e*544;
    xwT[(size_t)ld*544*81 + (size_t)k*81 + e] = xw[idx];
  } else if (idx < T1 + T2){
    int j = idx - T1;
    int ld = j / (544*DTR); int rem = j - ld*(544*DTR);
    int d = rem / DTR; int r = rem - d*DTR;
    dtwT[(size_t)ld*DTR*544 + (size_t)r*544 + d] = dtw[j];
  }
}

// ---------------------------------------------------------------- in_proj GEMM (rmsnorm fused)
__global__ __launch_bounds__(256) void k_inproj(
    const float* __restrict__ xb, const float* __restrict__ invr,
    const float* __restrict__ n1w, const float* __restrict__ inw,
    float* __restrict__ xz)
{
  __shared__ float As[16][76];
  __shared__ float Bs[16][76];
  const int tid = threadIdx.x;
  const int m0 = blockIdx.x << 6;
  const int nt = blockIdx.y;                    // 0..33
  const int dir = (nt >= 17) ? 1 : 0;
  const int n0l = (nt - dir*17) << 6;
  const float* wb = inw + (size_t)(dir*1088 + n0l)*272;
  const int tr = tid & 15, tc = tid >> 4;
  const int lr = tid >> 2, lk = (tid & 3) << 2;
  const float ivr = invr[m0 + lr];
  const float* xrow = xb + (size_t)(m0 + lr)*272;
  const float* wrow = wb + (size_t)lr*272;
  float acc[4][4];
#pragma unroll
  for (int i=0;i<4;i++)
#pragma unroll
    for (int j=0;j<4;j++) acc[i][j]=0.f;
  for (int k0=0;k0<272;k0+=16){
    float4 a4 = *(const float4*)(xrow + k0 + lk);
    float4 g4 = *(const float4*)(n1w + k0 + lk);
    float4 b4 = *(const float4*)(wrow + k0 + lk);
    As[lk+0][lr] = a4.x*ivr*g4.x;
    As[lk+1][lr] = a4.y*ivr*g4.y;
    As[lk+2][lr] = a4.z*ivr*g4.z;
    As[lk+3][lr] = a4.w*ivr*g4.w;
    Bs[lk+0][lr] = b4.x; Bs[lk+1][lr]=b4.y; Bs[lk+2][lr]=b4.z; Bs[lk+3][lr]=b4.w;
    __syncthreads();
#pragma unroll
    for (int kk=0;kk<16;kk++){
      float4 av = *(const float4*)(&As[kk][tr<<2]);
      float4 bv = *(const float4*)(&Bs[kk][tc<<2]);
      acc[0][0]+=av.x*bv.x; acc[0][1]+=av.x*bv.y; acc[0][2]+=av.x*bv.z; acc[0][3]+=av.x*bv.w;
      acc[1][0]+=av.y*bv.x; acc[1][1]+=av.y*bv.y; acc[1][2]+=av.y*bv.z; acc[1][3]+=av.y*bv.w;
      acc[2][0]+=av.z*bv.x; acc[2][1]+=av.z*bv.y; acc[2][2]+=av.z*bv.z; acc[2][3]+=av.z*bv.w;
      acc[3][0]+=av.w*bv.x; acc[3][1]+=av.w*bv.y; acc[3][2]+=av.w*bv.z; acc[3][3]+=av.w*bv.w;
    }
    __syncthreads();
  }
#pragma unroll
  for (int i=0;i<4;i++){
    int r = m0 + (tr<<2) + i;
    int b = r >> 9, t = r & 511;
    int ts = dir ? (511 - t) : t;
    float4 v = make_float4(acc[i][0],acc[i][1],acc[i][2],acc[i][3]);
    *(float4*)(xz + (size_t)((dir*NB + b)*SEQL + ts)*DXZ + n0l + (tc<<2)) = v;
  }
}

// ---------------------------------------------------------------- conv4+silu + x_proj + dt_proj
// block = 8 rows; writes xcT/dtT/zT channel-major [seg][d][t]
__global__ __launch_bounds__(256) void k_xdt(
  const float* __restrict__ xz, const float* __restrict__ cwl, const float* __restrict__ cbl,
  const float* __restrict__ xwTl, const float* __restrict__ dtwTl, const float* __restrict__ dtbl,
  float* __restrict__ xcT, float* __restrict__ dtT, float* __restrict__ zT,
  float* __restrict__ Bmg, float* __restrict__ Cmg)
{
  __shared__ float xcs[8][545];
  __shared__ float dts[8][DTR];
  const int tid = threadIdx.x;
  const int blk = blockIdx.x;        // 0..255
  const int seg = blk >> 6;          // dir*2 + b
  const int dir = seg >> 1;
  const int t0 = (blk & 63) << 3;
  const float* xzb  = xz + (size_t)seg*SEQL*DXZ;
  const float* cw   = cwl + dir*DI*4;
  const float* cb   = cbl + dir*DI;
  const float* xwT  = xwTl + (size_t)dir*DI*81;
  const float* dtwT = dtwTl + (size_t)dir*DTR*DI;
  const float* dtb  = dtbl + dir*DI;
  const size_t chb = (size_t)seg*DI;  // channel-row base

  // phase 1: conv4 + silu (+ z extract), row stores
  for (int j = tid; j < DI; j += 256){
    float4 w4 = *(const float4*)(cw + j*4);
    float bj = cb[j];
    float xv[11];
#pragma unroll
    for (int q=0; q<11; q++){
      int t = t0 + q - 3;
      xv[q] = (t >= 0) ? xzb[(size_t)t*DXZ + j] : 0.f;
    }
    float xo[8], zo[8];
#pragma unroll
    for (int rr=0; rr<8; rr++){
      float acc = bj + w4.x*xv[rr] + w4.y*xv[rr+1] + w4.z*xv[rr+2] + w4.w*xv[rr+3];
      float v = acc * sigmoid_fast(acc);
      xcs[rr][j] = v; xo[rr] = v;
      zo[rr] = xzb[(size_t)(t0+rr)*DXZ + 544 + j];
    }
    float* xr = xcT + (chb + j)*SEQL + t0;
    *(float4*)(xr)   = make_float4(xo[0],xo[1],xo[2],xo[3]);
    *(float4*)(xr+4) = make_float4(xo[4],xo[5],xo[6],xo[7]);
    float* zr = zT + (chb + j)*SEQL + t0;
    *(float4*)(zr)   = make_float4(zo[0],zo[1],zo[2],zo[3]);
    *(float4*)(zr+4) = make_float4(zo[4],zo[5],zo[6],zo[7]);
  }
  __syncthreads();

  // phase 2: x_proj — thread owns full length-544 dot(s), 648 outputs
  for (int idx = tid; idx < 648; idx += 256){
    int ta = idx / 81, e = idx - ta*81;
    const float* xr = xcs[ta];
    float a0=0.f,a1=0.f,a2=0.f,a3=0.f;
    for (int k=0; k<DI; k+=4){
      const float* wp = xwT + (size_t)k*81 + e;
      a0 = fmaf(xr[k],   wp[0],   a0);
      a1 = fmaf(xr[k+1], wp[81],  a1);
      a2 = fmaf(xr[k+2], wp[162], a2);
      a3 = fmaf(xr[k+3], wp[243], a3);
    }
    float acc = (a0+a1)+(a2+a3);
    size_t row = (size_t)seg*SEQL + t0 + ta;
    if (e < DTR)      dts[ta][e] = acc;
    else if (e < 49)  Bmg[row*DS + (e-DTR)] = acc;
    else              Cmg[row*DS + (e-49)] = acc;
  }
  __syncthreads();

  // phase 3: dt_proj + softplus, row stores to dtT
  {
    const int c1 = tid, c2 = tid+256;
    const bool h3 = tid < 32; const int c3 = 512 + tid;
    float w1[DTR], w2[DTR], w3[DTR];
#pragma unroll
    for (int q=0; q<DTR; q++){
      w1[q] = dtwT[q*DI + c1];
      w2[q] = dtwT[q*DI + c2];
      w3[q] = h3 ? dtwT[q*DI + c3] : 0.f;
    }
    float b1 = dtb[c1], b2 = dtb[c2], b3 = h3 ? dtb[c3] : 0.f;
    float o1[8], o2[8], o3[8];
#pragma unroll
    for (int rr=0; rr<8; rr++){
      float a1=b1, a2=b2, a3=b3;
#pragma unroll
      for (int q=0; q<DTR; q++){
        float dv = dts[rr][q];
        a1 = fmaf(w1[q],dv,a1); a2 = fmaf(w2[q],dv,a2); a3 = fmaf(w3[q],dv,a3);
      }
      o1[rr]=softplus_f(a1); o2[rr]=softplus_f(a2); o3[rr]=softplus_f(a3);
    }
    float* r1 = dtT + (chb + c1)*SEQL + t0;
    *(float4*)(r1)   = make_float4(o1[0],o1[1],o1[2],o1[3]);
    *(float4*)(r1+4) = make_float4(o1[4],o1[5],o1[6],o1[7]);
    float* r2 = dtT + (chb + c2)*SEQL + t0;
    *(float4*)(r2)   = make_float4(o2[0],o2[1],o2[2],o2[3]);
    *(float4*)(r2+4) = make_float4(o2[4],o2[5],o2[6],o2[7]);
    if (h3){
      float* r3 = dtT + (chb + c3)*SEQL + t0;
      *(float4*)(r3)   = make_float4(o3[0],o3[1],o3[2],o3[3]);
      *(float4*)(r3+4) = make_float4(o3[4],o3[5],o3[6],o3[7]);
    }
  }
}

// ---------------------------------------------------------------- chunked selective scan + gate
// all scan-side arrays channel-major [seg][d][t]
__global__ __launch_bounds__(128) void k_scan(
  const float* __restrict__ dtT, const float* __restrict__ xcT,
  const float* __restrict__ Bmg, const float* __restrict__ Cmg,
  const float* __restrict__ alogl, const float* __restrict__ dskl,
  const float* __restrict__ zT, float* __restrict__ yoT)
{
  __shared__ float hl[16][33], pl[16][33], Hi[16][33];
  const int d = blockIdx.x, b = blockIdx.y, dir = blockIdx.z;
  const int seg = dir*NB + b;
  const int tid = threadIdx.x;
  const int c = tid >> 3, sg = tid & 7, s0 = sg << 2;
  float A0,A1,A2,A3;
  {
    const float* al = alogl + (size_t)(dir*DI + d)*DS + s0;
    A0 = -expf(al[0]); A1 = -expf(al[1]); A2 = -expf(al[2]); A3 = -expf(al[3]);
  }
  const size_t cr = ((size_t)seg*DI + d)*SEQL;
  const float* dtr = dtT + cr;
  const float* xcr = xcT + cr;
  const float* zr  = zT  + cr;
  float* yor = yoT + cr;
  const float* Bp = Bmg + (size_t)seg*SEQL*DS + s0;
  const float* Cp = Cmg + (size_t)seg*SEQL*DS + s0;
  float h0=0,h1=0,h2=0,h3=0,p0=1,p1=1,p2=1,p3=1;
  const int tb = c << 5;
  for (int tq=0; tq<8; tq++){
    const int t4 = tb + (tq<<2);
    float4 dt4 = *(const float4*)(dtr + t4);
    const float* dtp4 = (const float*)&dt4;
    float4 xc4 = *(const float4*)(xcr + t4);
    const float* xcp4 = (const float*)&xc4;
#pragma unroll
    for (int u=0; u<4; u++){
      float ldt = dtp4[u], lxc = xcp4[u];
      float4 B4 = *(const float4*)(Bp + (size_t)(t4+u)*DS);
      float uu = ldt*lxc;
      float e;
      e = __expf(ldt*A0); h0 = fmaf(e,h0,uu*B4.x); p0*=e;
      e = __expf(ldt*A1); h1 = fmaf(e,h1,uu*B4.y); p1*=e;
      e = __expf(ldt*A2); h2 = fmaf(e,h2,uu*B4.z); p2*=e;
      e = __expf(ldt*A3); h3 = fmaf(e,h3,uu*B4.w); p3*=e;
    }
  }
  hl[c][s0]=h0; hl[c][s0+1]=h1; hl[c][s0+2]=h2; hl[c][s0+3]=h3;
  pl[c][s0]=p0; pl[c][s0+1]=p1; pl[c][s0+2]=p2; pl[c][s0+3]=p3;
  __syncthreads();
  if (tid < 32){
    float H = 0.f;
    Hi[0][tid] = 0.f;
    for (int cc=1; cc<16; cc++){
      H = fmaf(pl[cc-1][tid], H, hl[cc-1][tid]);
      Hi[cc][tid] = H;
    }
  }
  __syncthreads();
  h0=Hi[c][s0]; h1=Hi[c][s0+1]; h2=Hi[c][s0+2]; h3=Hi[c][s0+3];
  const float dsk = dskl[dir*DI + d];
  for (int tq=0; tq<8; tq++){
    const int t4 = tb + (tq<<2);
    float4 dt4 = *(const float4*)(dtr + t4);
    const float* dtp4 = (const float*)&dt4;
    float4 xc4 = *(const float4*)(xcr + t4);
    const float* xcp4 = (const float*)&xc4;
    float4 z4 = *(const float4*)(zr + t4);
    const float* zp4 = (const float*)&z4;
    float yv[4];
#pragma unroll
    for (int u=0; u<4; u++){
      float ldt = dtp4[u], lxc = xcp4[u];
      float4 B4 = *(const float4*)(Bp + (size_t)(t4+u)*DS);
      float4 C4 = *(const float4*)(Cp + (size_t)(t4+u)*DS);
      float uu = ldt*lxc;
      float e;
      e = __expf(ldt*A0); h0 = fmaf(e,h0,uu*B4.x);
      e = __expf(ldt*A1); h1 = fmaf(e,h1,uu*B4.y);
      e = __expf(ldt*A2); h2 = fmaf(e,h2,uu*B4.z);
      e = __expf(ldt*A3); h3 = fmaf(e,h3,uu*B4.w);
      float y = h0*C4.x + h1*C4.y + h2*C4.z + h3*C4.w;
      y += __shfl_xor(y,1); y += __shfl_xor(y,2); y += __shfl_xor(y,4);
      float z = zp4[u];
      yv[u] = fmaf(dsk, lxc, y) * (z * sigmoid_fast(z));
    }
    if (sg==0) *(float4*)(yor + t4) = make_float4(yv[0],yv[1],yv[2],yv[3]);
  }
}

// ---------------------------------------------------------------- out_proj GEMM (A = yoT channel-major)
__global__ __launch_bounds__(128) void k_outproj(
    const float* __restrict__ yoT, const float* __restrict__ ow, float* __restrict__ y12)
{
  __shared__ float As[16][68];
  __shared__ float Bs[16][40];
  const int tid = threadIdx.x;
  const int m0 = blockIdx.x << 6;
  const int n0 = blockIdx.y << 5;
  const int dir = blockIdx.z;
  const int bseg = m0 >> 9;
  const int t0 = m0 & 511;
  const float* At = yoT + (size_t)(dir*NB + bseg)*DI*SEQL;
  const float* W = ow + (size_t)dir*DM*DI;
  const int smi = (tid & 15) << 2;      // A-stage col (t within tile)
  const int skk = tid >> 4;             // A-stage k row 0..7
  const int lrb = tid >> 2, lkb = (tid & 3) << 2;
  const int tr = tid & 15, tc = tid >> 4;
  const int nb = n0 + lrb;
  const bool bvalid = nb < DM;
  const float* wrow = W + (size_t)(bvalid ? nb : 0)*DI;
  float acc[4][4];
#pragma unroll
  for (int i=0;i<4;i++)
#pragma unroll
    for (int j=0;j<4;j++) acc[i][j]=0.f;
  for (int k0=0;k0<544;k0+=16){
    float4 a0 = *(const float4*)(At + (size_t)(k0+skk)*SEQL + t0 + smi);
    float4 a1 = *(const float4*)(At + (size_t)(k0+skk+8)*SEQL + t0 + smi);
    *(float4*)(&As[skk][smi])   = a0;
    *(float4*)(&As[skk+8][smi]) = a1;
    float4 b4 = bvalid ? *(const float4*)(wrow + k0 + lkb) : make_float4(0.f,0.f,0.f,0.f);
    Bs[lkb+0][lrb]=b4.x; Bs[lkb+1][lrb]=b4.y; Bs[lkb+2][lrb]=b4.z; Bs[lkb+3][lrb]=b4.w;
    __syncthreads();
#pragma unroll
    for (int kk=0;kk<16;kk++){
      float4 av = *(const float4*)(&As[kk][tr<<2]);
      float4 bv = *(const float4*)(&Bs[kk][tc<<2]);
      acc[0][0]+=av.x*bv.x; acc[0][1]+=av.x*bv.y; acc[0][2]+=av.x*bv.z; acc[0][3]+=av.x*bv.w;
      acc[1][0]+=av.y*bv.x; acc[1][1]+=av.y*bv.y; acc[1][2]+=av.y*bv.z; acc[1][3]+=av.y*bv.w;
      acc[2][0]+=av.z*bv.x; acc[2][1]+=av.z*bv.y; acc[2][2]+=av.z*bv.z; acc[2][3]+=av.z*bv.w;
      acc[3][0]+=av.w*bv.x; acc[3][1]+=av.w*bv.y; acc[3][2]+=av.w*bv.z; acc[3][3]+=av.w*bv.w;
    }
    __syncthreads();
  }
  int col = n0 + (tc<<2);
  if (col < DM){
#pragma unroll
    for (int i=0;i<4;i++){
      int r = m0 + (tr<<2) + i;
      int b = r >> 9, t = r & 511;
      int ts = dir ? (511 - t) : t;
      float4 v = make_float4(acc[i][0],acc[i][1],acc[i][2],acc[i][3]);
      *(float4*)(y12 + (size_t)dir*ROWS*DM + (size_t)(b*SEQL+ts)*DM + col) = v;
    }
  }
}

// ---------------------------------------------------------------- combine
__global__ __launch_bounds__(256) void k_combine(
  const float* __restrict__ y12, const float* __restrict__ lamq,
  const float* __restrict__ n2w, float* __restrict__ xb,
  float* __restrict__ invr, float lam_init, float omli)
{
  __shared__ float sred[4];
  const int tid = threadIdx.x;
  const int r = blockIdx.x;
  const float* y1 = y12 + (size_t)r*DM;
  const float* y2 = y12 + (size_t)ROWS*DM + (size_t)r*DM;
  float lp = lamq[tid];
  if (tid < 16) lp += lamq[tid+256];
  float lsum = block_reduce_256(lp, sred, tid);
  float lam = sigmoid_fast(lsum) + lam_init;
  float a0 = y1[tid] - lam*y2[tid];
  float a1 = 0.f;
  if (tid<16) a1 = y1[tid+256] - lam*y2[tid+256];
  float ss = block_reduce_256(a0*a0 + a1*a1, sred, tid);
  float rms = rsqrtf(ss*(1.f/DM) + 1e-5f);
  float xo0 = xb[(size_t)r*DM + tid] + a0*rms*n2w[tid]*omli;
  float xo1 = 0.f;
  if (tid<16) xo1 = xb[(size_t)r*DM + tid+256] + a1*rms*n2w[tid+256]*omli;
  xb[(size_t)r*DM+tid] = xo0;
  if (tid<16) xb[(size_t)r*DM+tid+256] = xo1;
  float ss2 = block_reduce_256(xo0*xo0 + xo1*xo1, sred, tid);
  if (tid==0) invr[r] = rsqrtf(ss2*(1.f/DM) + 1e-5f);
}

// ---------------------------------------------------------------- head
__global__ __launch_bounds__(256) void k_head1(const float* __restrict__ xb, float* __restrict__ xmp){
  int ch = blockIdx.x, b = blockIdx.y, tid = threadIdx.x;
  int t0 = ch*64;
  float s0=0.f, s1=0.f;
  for (int t=t0; t<t0+64; t++){
    const float* row = xb + (size_t)(b*SEQL+t)*DM;
    s0 += row[tid];
    if (tid<16) s1 += row[tid+256];
  }
  xmp[(size_t)(b*8+ch)*DM + tid] = s0;
  if (tid<16) xmp[(size_t)(b*8+ch)*DM + tid+256] = s1;
}

__global__ __launch_bounds__(256) void k_head2(
  const float* __restrict__ xmp, const float* __restrict__ yin,
  const float* __restrict__ mlpw, const float* __restrict__ mlpb,
  const float* __restrict__ pw, const float* __restrict__ pb,
  float* __restrict__ out)
{
  __shared__ float xm[2][DM];
  __shared__ float x2s[2][DM];
  __shared__ float sred[4];
  int tid = threadIdx.x;
  for (int idx=tid; idx<2*DM; idx+=256){
    int b = idx / DM, c = idx - b*DM;
    float s=0.f;
    for (int ch=0; ch<8; ch++) s += xmp[(size_t)(b*8+ch)*DM + c];
    xm[b][c] = s * (1.f/SEQL);
  }
  __syncthreads();
  for (int idx=tid; idx<2*DM; idx+=256){
    int b = idx / DM, c = idx - b*DM;
    float acc = mlpb[c];
    const float* wr = mlpw + (size_t)c*DM;
    for (int k=0;k<DM;k++) acc += wr[k]*xm[b][k];
    float v = fmaxf(acc, 0.f);
    x2s[b][c] = v;
    out[2 + b*DM + c] = v;
  }
  __syncthreads();
  for (int b=0;b<2;b++){
    float p = x2s[b][tid]*pw[tid];
    if (tid<16) p += x2s[b][tid+256]*pw[tid+256];
    float tot = block_reduce_256(p, sred, tid);
    if (tid==0) out[b] = tot + yin[b]*pw[DM] + pb[0];
  }
}

// ----------------------------------------------------------------
extern "C" void kernel_launch(void* const* d_in, const int* in_sizes, int n_in,
                              void* d_out, int out_size, void* d_ws, size_t ws_size,
                              hipStream_t stream)
{
  const float* x0     = (const float*)d_in[0];
  const float* yin    = (const float*)d_in[1];
  const float* in_w   = (const float*)d_in[2];
  const float* conv_w = (const float*)d_in[3];
  const float* conv_b = (const float*)d_in[4];
  const float* x_w    = (const float*)d_in[5];
  const float* dt_w   = (const float*)d_in[6];
  const float* dt_b   = (const float*)d_in[7];
  const float* a_log  = (const float*)d_in[8];
  const float* dskip  = (const float*)d_in[9];
  const float* out_w  = (const float*)d_in[10];
  const float* lamq   = (const float*)d_in[11];
  const float* n1w    = (const float*)d_in[12];
  const float* n2w    = (const float*)d_in[13];
  const float* mlpw   = (const float*)d_in[14];
  const float* mlpb   = (const float*)d_in[15];
  const float* pw     = (const float*)d_in[16];
  const float* pb     = (const float*)d_in[17];

  float* ws  = (float*)d_ws;
  float* xb  = ws + OFF_X;
  float* invr= ws + OFF_INVR;
  float* xz  = ws + OFF_XZ;
  float* xcT = ws + OFF_XCT;
  float* dtT = ws + OFF_DTT;
  float* zT  = ws + OFF_ZT;
  float* Bm  = ws + OFF_BM;
  float* Cm  = ws + OFF_CM;
  float* yoT = ws + OFF_YOT;
  float* y12 = ws + OFF_Y12;
  float* xmp = ws + OFF_XMP;
  float* xwT = ws + OFF_XWT;
  float* dtwT= ws + OFF_DTWT;
  float* outp = (float*)d_out;

  k_transpose<<<(24*81*544 + 24*544*DTR + 255)/256, 256, 0, stream>>>(x_w, dt_w, xwT, dtwT);
  k_init<<<ROWS, 64, 0, stream>>>(x0, xb, invr);
  for (int i=0;i<NL;i++){
    float lam_init = 0.8f - 0.6f*expf(-0.3f*(float)i);
    k_inproj<<<dim3(16,34), 256, 0, stream>>>(xb, invr, n1w + (size_t)i*DM,
        in_w + (size_t)i*2176*272, xz);
    k_xdt<<<256, 256, 0, stream>>>(xz,
        conv_w + (size_t)i*2*DI*4, conv_b + (size_t)i*2*DI,
        xwT + (size_t)i*2*DI*81, dtwT + (size_t)i*2*DTR*DI, dt_b + (size_t)i*2*DI,
        xcT, dtT, zT, Bm, Cm);
    k_scan<<<dim3(DI,NB,2), 128, 0, stream>>>(dtT, xcT, Bm, Cm,
        a_log + (size_t)i*2*DI*DS, dskip + (size_t)i*2*DI, zT, yoT);
    k_outproj<<<dim3(16,9,2), 128, 0, stream>>>(yoT, out_w + (size_t)i*2*DM*DI, y12);
    k_combine<<<ROWS, 256, 0, stream>>>(y12, lamq + (size_t)i*DM, n2w + (size_t)i*DM,
        xb, invr, lam_init, 1.f - lam_init);
  }
  k_head1<<<dim3(8,2), 256, 0, stream>>>(xb, xmp);
  k_head2<<<1, 256, 0, stream>>>(xmp, yin, mlpw, mlpb, pw, pb, outp);
}